// Round 7
// baseline (130.316 us; speedup 1.0000x reference)
//
#include <hip/hip_runtime.h>

// GAGKNNQueryAndGroup: B=4, N=8192, NPOINT=2048, C=64, NSAMPLE=32, LAMBDA=0.5
// Output: (B, 3+C, NPOINT, NS) f32
//
// LAMBDA == 0.5 makes the component mask numerically irrelevant (d*0.5 both
// branches, order-preserving) -> components unused. Output is gathered data
// only, so monotone distance rescales leave results bit-identical.

#define BQ 4
#define NN_ 8192
#define NPOINT 2048
#define CF 64
#define NS 32
#define T1 256
#define PER (NN_ / T1)   // 32 points per thread
#define QB 8             // queries per block (knn)
#define CAPQ 128         // per-query candidate capacity (expected ~44)
#define M_EPS 1e-3f      // >> |fma-form - exact| rounding gap (~1e-5)

#define KNN_BLOCKS (BQ * NPOINT / QB)            // 1024
#define TR_BLOCKS  ((NN_ / 32) * (CF / 32) * BQ) // 2048

// LDS arena (12,416B -> 8 blocks/CU, thread-capped, 100% wave ceiling):
//  region A (8192B): sMin[QB][T1] (pass1) / keys[QB][CAPQ] u64 (rank) /
//                    tr[32][33] (transpose path) -- phases disjoint.
//  region B (4096B): candI[QB][CAPQ] u32 (candidate indices)
//  region C (64B):   sTheta[QB] + cnt[QB]
#define REG_A (QB * T1 * 4)
#define REG_B (QB * CAPQ * 4)
#define SMEM_BYTES (REG_A + REG_B + QB * 4 + QB * 4)

__device__ __forceinline__ float rfl(float x) {
  return __int_as_float(__builtin_amdgcn_readfirstlane(__float_as_int(x)));
}

__global__ __launch_bounds__(256) void knn_tr_kernel(
    const float* __restrict__ xyz, const float* __restrict__ new_xyz,
    const float* __restrict__ features, int* __restrict__ idxOut,
    float* __restrict__ featsT) {
  __shared__ __align__(16) char smem[SMEM_BYTES];
  const int tid = threadIdx.x;

  if (blockIdx.x >= KNN_BLOCKS) {
    // ---------------- transpose path: features (B,C,N) -> (B,N,C) ----------
    float(*tr)[33] = (float(*)[33])smem;
    const int t = blockIdx.x - KNN_BLOCKS;
    const int n0 = (t & 255) * 32;
    const int c0 = ((t >> 8) & 1) * 32;
    const int b = t >> 9;
    const int tx = tid & 31;
    const int ty = tid >> 5;   // 0..7
#pragma unroll
    for (int i = 0; i < 4; i++) {
      int c = c0 + ty + i * 8;
      tr[ty + i * 8][tx] = features[(size_t)b * CF * NN_ + (size_t)c * NN_ + n0 + tx];
    }
    __syncthreads();
#pragma unroll
    for (int i = 0; i < 4; i++) {
      int nrow = n0 + ty + i * 8;
      featsT[(size_t)b * NN_ * CF + (size_t)nrow * CF + c0 + tx] = tr[tx][ty + i * 8];
    }
    return;
  }

  // ---------------- knn path: exact top-32, 8 queries/block ----------------
  // Pass 1 (rolled): fma-form score t = pp - 2 p.q (qx2 = -2 qx in SGPR).
  // theta_k = (32nd-smallest of 64 disjoint 128-point group minima) + |q|^2
  // + M_EPS: guaranteed upper bound on the true 32nd-smallest EXACT distance.
  // Pass 2 (rolled, tiny body): push candidate INDEX only for t <= th2.
  // Rank phase: recompute bit-exact reference distance for the ~44 candidates
  // per query, stable rank by (d_bits, idx). Extras with d>theta rank >=32 and
  // fall out naturally. Hot-loop code stays small -> I-cache resident.
  float(*sMin)[T1] = (float(*)[T1])smem;                         // region A
  unsigned long long(*keys)[CAPQ] = (unsigned long long(*)[CAPQ])smem;  // A, after pass1
  unsigned int(*candI)[CAPQ] = (unsigned int(*)[CAPQ])(smem + REG_A);   // region B
  float* sTheta = (float*)(smem + REG_A + REG_B);
  int* cnt = (int*)(smem + REG_A + REG_B + QB * 4);

  const int tile = blockIdx.x;
  const int b = tile / (NPOINT / QB);
  const int q0 = b * NPOINT + (tile % (NPOINT / QB)) * QB;
  const int lane = tid & 63;
  const int wid = tid >> 6;

  // Block-uniform query constants -> SGPRs (readfirstlane).
  float qx2[QB], qy2[QB], qz2[QB], qnn[QB];
#pragma unroll
  for (int k = 0; k < QB; k++) {
    float ax = new_xyz[(q0 + k) * 3 + 0];
    float ay = new_xyz[(q0 + k) * 3 + 1];
    float az = new_xyz[(q0 + k) * 3 + 2];
    qx2[k] = rfl(-2.0f * ax);
    qy2[k] = rfl(-2.0f * ay);
    qz2[k] = rfl(-2.0f * az);
    qnn[k] = rfl(ax * ax + ay * ay + az * az);
  }

  const float4* __restrict__ base4 = (const float4*)(xyz + (size_t)b * NN_ * 3);

  float smin_r[QB];
#pragma unroll
  for (int k = 0; k < QB; k++) smin_r[k] = 3.4e38f;

  // ---- Pass 1 (rolled: keep code small; I-cache was the R4/R5 bottleneck) ----
#pragma unroll 2
  for (int g = 0; g < PER / 4; g++) {          // 8 groups x 4 consecutive points
    const int v = g * 768 + tid * 3;           // float4 index of 48B group
    float4 v0 = base4[v + 0];                  // x0 y0 z0 x1
    float4 v1 = base4[v + 1];                  // y1 z1 x2 y2
    float4 v2 = base4[v + 2];                  // z2 x3 y3 z3
    float xs[4] = {v0.x, v0.w, v1.z, v2.y};
    float ys[4] = {v0.y, v1.x, v1.w, v2.z};
    float zs[4] = {v0.z, v1.y, v2.x, v2.w};
#pragma unroll
    for (int i = 0; i < 4; i++) {
      float pp = fmaf(zs[i], zs[i], fmaf(ys[i], ys[i], xs[i] * xs[i]));
#pragma unroll
      for (int k = 0; k < QB; k++) {
        float t = fmaf(xs[i], qx2[k], pp);
        t = fmaf(ys[i], qy2[k], t);
        t = fmaf(zs[i], qz2[k], t);
        smin_r[k] = fminf(smin_r[k], t);
      }
    }
  }

#pragma unroll
  for (int k = 0; k < QB; k++) sMin[k][tid] = smin_r[k];
  if (tid < QB) cnt[tid] = 0;
  __syncthreads();

  // ---- theta: wave w handles queries 2w,2w+1 (64-lane register bitonic) ----
#pragma unroll
  for (int t2 = 0; t2 < 2; t2++) {
    const int k = wid * 2 + t2;
    float m = fminf(fminf(sMin[k][lane], sMin[k][lane + 64]),
                    fminf(sMin[k][lane + 128], sMin[k][lane + 192]));
#pragma unroll
    for (int kk = 2; kk <= 64; kk <<= 1) {
#pragma unroll
      for (int jj = kk >> 1; jj > 0; jj >>= 1) {
        float o = __shfl_xor(m, jj);
        bool up = ((lane & kk) == 0);
        bool lower = ((lane & jj) == 0);
        m = (up == lower) ? fminf(m, o) : fmaxf(m, o);
      }
    }
    if (lane == 31) sTheta[k] = m + qnn[k] + M_EPS;   // d-space upper bound
  }
  __syncthreads();

  float th2[QB];
#pragma unroll
  for (int k = 0; k < QB; k++)
    th2[k] = rfl(sTheta[k] + M_EPS - qnn[k]);   // prefilter bound (t-space)

  // ---- Pass 2 (rolled, tiny rare-path: push index only) ----
#pragma unroll 1
  for (int g = 0; g < PER / 4; g++) {
    const int v = g * 768 + tid * 3;
    float4 v0 = base4[v + 0];
    float4 v1 = base4[v + 1];
    float4 v2 = base4[v + 2];
    float xs[4] = {v0.x, v0.w, v1.z, v2.y};
    float ys[4] = {v0.y, v1.x, v1.w, v2.z};
    float zs[4] = {v0.z, v1.y, v2.x, v2.w};
#pragma unroll
    for (int i = 0; i < 4; i++) {
      float pp = fmaf(zs[i], zs[i], fmaf(ys[i], ys[i], xs[i] * xs[i]));
      const int n = g * 1024 + tid * 4 + i;
#pragma unroll
      for (int k = 0; k < QB; k++) {
        float t = fmaf(xs[i], qx2[k], pp);
        t = fmaf(ys[i], qy2[k], t);
        t = fmaf(zs[i], qz2[k], t);
        if (t <= th2[k]) {
          int pos = atomicAdd(&cnt[k], 1);
          if (pos < CAPQ) candI[k][pos] = (unsigned)n;
        }
      }
    }
  }
  __syncthreads();

  // ---- Rank phase: exact distance + stable (d_bits, idx) rank per query ----
  const float* __restrict__ baseF = xyz + (size_t)b * NN_ * 3;
#pragma unroll
  for (int t2 = 0; t2 < 2; t2++) {
    const int k = wid * 2 + t2;
    const int qq = q0 + k;
    const int m = cnt[k] < CAPQ ? cnt[k] : CAPQ;
    // raw query coords (bit-exact reference values)
    const float qxk = new_xyz[qq * 3 + 0];
    const float qyk = new_xyz[qq * 3 + 1];
    const float qzk = new_xyz[qq * 3 + 2];

    unsigned long long keyreg[CAPQ / 64];
#pragma unroll
    for (int c = 0; c < CAPQ / 64; c++) {
      const int i = lane + c * 64;
      if (i < m) {
        const int n = (int)candI[k][i];
        float dx = baseF[n * 3 + 0] - qxk;
        float dy = baseF[n * 3 + 1] - qyk;
        float dz = baseF[n * 3 + 2] - qzk;
        // bit-exact reference distance: no FMA contraction, left-to-right sum
        float d = __fadd_rn(__fadd_rn(__fmul_rn(dx, dx), __fmul_rn(dy, dy)),
                            __fmul_rn(dz, dz));
        keyreg[c] = ((unsigned long long)__float_as_uint(d) << 32) | (unsigned)n;
      }
    }
    __syncthreads();   // candI fully read -> safe even if regions were reused
#pragma unroll
    for (int c = 0; c < CAPQ / 64; c++) {
      const int i = lane + c * 64;
      if (i < m) keys[k][i] = keyreg[c];
    }
    __syncthreads();   // keys visible to all lanes
#pragma unroll
    for (int c = 0; c < CAPQ / 64; c++) {
      const int i = lane + c * 64;
      if (i < m) {
        unsigned long long x = keys[k][i];
        int r = 0;
        for (int j = 0; j < m; j++) r += (keys[k][j] < x) ? 1 : 0;
        if (r < NS) idxOut[qq * NS + r] = (int)(x & 0xffffffffu);
      }
    }
    __syncthreads();
  }
}

// ---------------- Phase 2: gather + grouped write (R6: rewritten) ----------
// 2 queries/block (4096 blocks). Staging is c-major (ldsFT[c][s], stride 40
// floats): staging dword-writes are bank-conflict-free (2-way across wave
// halves = free), and the output loop reads contiguous 16B-aligned float4s
// across s -> 5 global_store_dwordx4 per thread instead of 9 dword stores.
#define QG 2
#define CSTR 40   // LDS row stride (floats): mult of 4 (16B-aligned float4 reads)
__global__ __launch_bounds__(256) void group_kernel(const float* __restrict__ xyz,
                                                    const float* __restrict__ new_xyz,
                                                    const float* __restrict__ featsT,
                                                    const int* __restrict__ idxArr,
                                                    float* __restrict__ out) {
  const int q0 = blockIdx.x * QG;
  const int tid = threadIdx.x;
  const int ql = tid >> 7;          // local query 0..1 (waves don't straddle)
  const int t = tid & 127;          // lane within this query's 128 threads
  const int q = q0 + ql;
  const int b = q / NPOINT;
  const int p = q - b * NPOINT;

  __shared__ int sIdx[QG][NS];
  __shared__ __align__(16) float ldsX[QG][3][NS];
  __shared__ __align__(16) float ldsFT[QG][CF][CSTR];

  if (tid < QG * NS)
    sIdx[tid >> 5][tid & 31] = idxArr[(q0 + (tid >> 5)) * NS + (tid & 31)];
  __syncthreads();

  {
    // 128 threads/query = 32 samples x 4 readers; reader r pulls the
    // contiguous 64B chunk c = [16r, 16r+16) of the 256B feature row,
    // then scatters it c-major into LDS (bank-free: s distinct per lane).
    const int s = t & 31, r = t >> 5;   // r in 0..3
    const int nn = sIdx[ql][s];
    const float4* src =
        (const float4*)(featsT + ((size_t)b * NN_ + nn) * CF) + r * 4;
    float4 v0 = src[0], v1 = src[1], v2 = src[2], v3 = src[3];
    const int c0 = r * 16;
    ldsFT[ql][c0 + 0][s] = v0.x;  ldsFT[ql][c0 + 1][s] = v0.y;
    ldsFT[ql][c0 + 2][s] = v0.z;  ldsFT[ql][c0 + 3][s] = v0.w;
    ldsFT[ql][c0 + 4][s] = v1.x;  ldsFT[ql][c0 + 5][s] = v1.y;
    ldsFT[ql][c0 + 6][s] = v1.z;  ldsFT[ql][c0 + 7][s] = v1.w;
    ldsFT[ql][c0 + 8][s] = v2.x;  ldsFT[ql][c0 + 9][s] = v2.y;
    ldsFT[ql][c0 + 10][s] = v2.z; ldsFT[ql][c0 + 11][s] = v2.w;
    ldsFT[ql][c0 + 12][s] = v3.x; ldsFT[ql][c0 + 13][s] = v3.y;
    ldsFT[ql][c0 + 14][s] = v3.z; ldsFT[ql][c0 + 15][s] = v3.w;
  }
  if (t < 96) {
    const int dd = t >> 5, s = t & 31;
    const int nn = sIdx[ql][s];
    ldsX[ql][dd][s] = xyz[((size_t)b * NN_ + nn) * 3 + dd] -
                      new_xyz[(size_t)q * 3 + dd];
  }
  __syncthreads();

  // Output: 67 rows x 32 floats. Thread (g = t&7, row0 = t>>3) writes float4
  // at samples [4g,4g+4) for rows row0, row0+16, ... (5 iters, guard row<67).
  const int g = t & 7;
  const int row0 = t >> 3;
#pragma unroll
  for (int it = 0; it < 5; it++) {
    const int row = row0 + it * 16;
    if (row < 67) {
      float4 v;
      if (row < 3) v = *(const float4*)&ldsX[ql][row][g * 4];
      else         v = *(const float4*)&ldsFT[ql][row - 3][g * 4];
      *(float4*)&out[(((size_t)b * 67 + row) * NPOINT + p) * NS + g * 4] = v;
    }
  }
}

extern "C" void kernel_launch(void* const* d_in, const int* in_sizes, int n_in,
                              void* d_out, int out_size, void* d_ws, size_t ws_size,
                              hipStream_t stream) {
  const float* xyz      = (const float*)d_in[0];   // (4,8192,3)
  const float* new_xyz  = (const float*)d_in[1];   // (4,2048,3)
  // d_in[2], d_in[3]: components — unused (LAMBDA=0.5 makes mask a no-op)
  const float* features = (const float*)d_in[4];   // (4,64,8192)
  float* out = (float*)d_out;

  // workspace layout: [idx: 4*2048*32 int = 1MB][featsT: 4*8192*64 f32 = 8MB]
  int* idxArr = (int*)d_ws;
  float* featsT = (float*)((char*)d_ws + (size_t)BQ * NPOINT * NS * sizeof(int));

  knn_tr_kernel<<<KNN_BLOCKS + TR_BLOCKS, T1, 0, stream>>>(xyz, new_xyz, features,
                                                           idxArr, featsT);
  group_kernel<<<BQ * NPOINT / QG, T1, 0, stream>>>(xyz, new_xyz, featsT, idxArr, out);
}